// Round 2
// baseline (308.527 us; speedup 1.0000x reference)
//
#include <hip/hip_runtime.h>
#include <hip/hip_bf16.h>
#include <math.h>

// Problem constants (from reference setup_inputs)
#define T_TOKENS 16384
#define DIM      2048
#define NEXP     64
#define TOPK     2

// Flat fp32 output layout: combine | topk_idx | gates | expert_activation
#define OFF_COMBINE 0
#define OFF_IDX     (T_TOKENS * NEXP)
#define OFF_GATES   (OFF_IDX + T_TOKENS * TOPK)
#define OFF_ACT     (OFF_GATES + T_TOKENS * TOPK)

#define PSTR 68                 // padded LDS row stride (floats); 272B = 17*16B
#define WT_PLANE (NEXP * DIM)   // one bf16 plane of transposed w, in elements

typedef __attribute__((ext_vector_type(8))) short  short8;   // 8 bf16 in 4 VGPRs
typedef __attribute__((ext_vector_type(4))) float  f32x4;

#define MFMA16(a, b, c) __builtin_amdgcn_mfma_f32_16x16x32_bf16((a), (b), (c), 0, 0, 0)

// Static device storage for the transposed/split weights: 3 bf16 planes
// (h, m, l) of wt[e][k] => 3*64*2048*2B = 768 KB. Module-load allocated —
// no dependence on d_ws (round-1 container death was consistent with an
// OOB write into an undersized/null workspace).
__device__ __align__(16) unsigned short g_wt[3 * WT_PLANE];

__device__ __forceinline__ unsigned short bf16_bits(__hip_bfloat16 h) {
    return __builtin_bit_cast(unsigned short, h);
}

// ---------------------------------------------------------------------------
// Setup: transpose w [DIM][NEXP] -> wt [e][k] and 3-way bf16 split (h,m,l).
// r1 = w - h and r2 = r1 - m are exact fp32 subtractions, so h+m+l carries
// ~24 mantissa bits of w. Also zeroes expert_activation.
// ---------------------------------------------------------------------------
__global__ void wsplit_kernel(const float* __restrict__ w,
                              float* __restrict__ out) {
    const int tid = threadIdx.x;
    if (blockIdx.x == 0 && tid < NEXP) out[OFF_ACT + tid] = 0.0f;

    const int krow = blockIdx.x * 16 + (tid >> 4);   // grid = DIM/16 blocks
    const int e0   = (tid & 15) * 4;
    const float4 v = *reinterpret_cast<const float4*>(w + (size_t)krow * NEXP + e0);
    const float f[4] = {v.x, v.y, v.z, v.w};
    #pragma unroll
    for (int m = 0; m < 4; ++m) {
        const int e  = e0 + m;
        const float val = f[m];
        const __hip_bfloat16 h  = __float2bfloat16(val);
        const float r1          = val - __bfloat162float(h);
        const __hip_bfloat16 mm = __float2bfloat16(r1);
        const float r2          = r1 - __bfloat162float(mm);
        const __hip_bfloat16 lo = __float2bfloat16(r2);
        g_wt[(size_t)e * DIM + krow]                = bf16_bits(h);
        g_wt[(size_t)e * DIM + krow + WT_PLANE]     = bf16_bits(mm);
        g_wt[(size_t)e * DIM + krow + 2 * WT_PLANE] = bf16_bits(lo);
    }
}

// ---------------------------------------------------------------------------
// Router: one block = 64 tokens, 256 threads = 4 waves.
// Wave wv owns tokens [wv*16, wv*16+16); each wave computes a 16x64 score
// tile over K=2048 with mfma_f32_16x16x32_bf16 (4 expert frags x 6
// split-products per K-step). A comes straight from global x (fp32 ->
// 3-way bf16 split in registers, depth-4 ring to cover the HBM BDP);
// B comes from the pre-transposed g_wt planes (L1/L2-resident, depth-2
// ring). No barriers in the main loop.
// ---------------------------------------------------------------------------
__global__ __launch_bounds__(256, 1)
void router_kernel(const float* __restrict__ x,
                   const float* __restrict__ noise,
                   float* __restrict__ out) {
    __shared__ float part[64][PSTR];   // final scores (pre-noise), 17.4 KB
    __shared__ float nsh[64][PSTR];    // staged noise
    __shared__ float g1s[64], g2s[64];
    __shared__ int   i1s[64], i2s[64];
    __shared__ float bins[NEXP];

    const int tid  = threadIdx.x;
    const int l    = tid & 63;
    const int wv   = tid >> 6;        // 0..3: 16-token group
    const int lrow = l & 15;          // MFMA row / col within fragment
    const int lk   = l >> 4;          // k-subgroup (0..3) * 8
    const int brow = blockIdx.x * 64;

    if (tid < NEXP) bins[tid] = 0.0f;

    // Stage this block's noise rows, fully coalesced.
    #pragma unroll
    for (int i = 0; i < 4; ++i) {
        const int idx = tid + i * 256;
        const int r = idx >> 4, c = (idx & 15) * 4;
        *reinterpret_cast<float4*>(&nsh[r][c]) =
            *reinterpret_cast<const float4*>(noise + (size_t)(brow + r) * NEXP + c);
    }

    // A: lane reads x[row = brow + wv*16 + lrow][k = s*32 + lk*8 .. +8]
    const float* xa = x + (size_t)(brow + wv * 16 + lrow) * DIM + lk * 8;
    // B: lane reads wt[e = n*16 + lrow][k = s*32 + lk*8 .. +8] per plane
    const unsigned short* wb[4];
    #pragma unroll
    for (int n = 0; n < 4; ++n)
        wb[n] = g_wt + (size_t)(n * 16 + lrow) * DIM + lk * 8;

    f32x4 acc[4];
    #pragma unroll
    for (int n = 0; n < 4; ++n) acc[n] = (f32x4){0.0f, 0.0f, 0.0f, 0.0f};

    // Register rings. A: depth 4 (need ~22KB/CU in flight to saturate HBM;
    // 4 steps x 32B/lane x 4 waves = 32KB). W: depth 2 (L1/L2 latency only).
    float4 XA[4][2];
    short8 WH[2][4], WM[2][4], WL[2][4];

    #pragma unroll
    for (int s = 0; s < 4; ++s) {
        XA[s][0] = *reinterpret_cast<const float4*>(xa + s * 32);
        XA[s][1] = *reinterpret_cast<const float4*>(xa + s * 32 + 4);
    }
    #pragma unroll
    for (int s = 0; s < 2; ++s) {
        #pragma unroll
        for (int n = 0; n < 4; ++n) {
            WH[s][n] = *reinterpret_cast<const short8*>(wb[n] + s * 32);
            WM[s][n] = *reinterpret_cast<const short8*>(wb[n] + s * 32 + WT_PLANE);
            WL[s][n] = *reinterpret_cast<const short8*>(wb[n] + s * 32 + 2 * WT_PLANE);
        }
    }

    // 64 K-steps of 32 k's. unroll 4 keeps both ring indices (s&3, s&1)
    // compile-time constant (no scratch-spilled register arrays).
    #pragma unroll 4
    for (int s = 0; s < 64; ++s) {
        const int sa = s & 3;
        const int su = s & 1;

        // ---- convert A slot: fp32 -> (ah, am, al) bf16 split
        float xr[8];
        xr[0] = XA[sa][0].x; xr[1] = XA[sa][0].y; xr[2] = XA[sa][0].z; xr[3] = XA[sa][0].w;
        xr[4] = XA[sa][1].x; xr[5] = XA[sa][1].y; xr[6] = XA[sa][1].z; xr[7] = XA[sa][1].w;
        short8 ah, am, al;
        #pragma unroll
        for (int i = 0; i < 8; ++i) {
            const float f0 = xr[i];
            const __hip_bfloat16 h  = __float2bfloat16(f0);
            const float r1          = f0 - __bfloat162float(h);
            const __hip_bfloat16 m  = __float2bfloat16(r1);
            const float r2          = r1 - __bfloat162float(m);
            const __hip_bfloat16 lo = __float2bfloat16(r2);
            ah[i] = (short)bf16_bits(h);
            am[i] = (short)bf16_bits(m);
            al[i] = (short)bf16_bits(lo);
        }

        // ---- prefetch A for s+4 into the slot just consumed
        // (tail clamp to 63: s=59 correctly feeds s=63; later loads unused)
        const int sA = (s + 4 < 64) ? (s + 4) : 63;
        XA[sa][0] = *reinterpret_cast<const float4*>(xa + sA * 32);
        XA[sa][1] = *reinterpret_cast<const float4*>(xa + sA * 32 + 4);

        // ---- 6 split-products per expert fragment (terms kept to 2^-16):
        //      h*h + h*m + m*h + h*l + m*m + l*h
        #pragma unroll
        for (int n = 0; n < 4; ++n) {
            acc[n] = MFMA16(ah, WH[su][n], acc[n]);
            acc[n] = MFMA16(ah, WM[su][n], acc[n]);
            acc[n] = MFMA16(am, WH[su][n], acc[n]);
            acc[n] = MFMA16(ah, WL[su][n], acc[n]);
            acc[n] = MFMA16(am, WM[su][n], acc[n]);
            acc[n] = MFMA16(al, WH[su][n], acc[n]);
        }

        // ---- prefetch W for s+2 into the slot just consumed
        const int sW = (s + 2 < 64) ? (s + 2) : s;
        #pragma unroll
        for (int n = 0; n < 4; ++n) {
            WH[su][n] = *reinterpret_cast<const short8*>(wb[n] + sW * 32);
            WM[su][n] = *reinterpret_cast<const short8*>(wb[n] + sW * 32 + WT_PLANE);
            WL[su][n] = *reinterpret_cast<const short8*>(wb[n] + sW * 32 + 2 * WT_PLANE);
        }
    }

    // C/D layout (m89-verified): col = lane&15, row = (lane>>4)*4 + reg.
    #pragma unroll
    for (int n = 0; n < 4; ++n) {
        #pragma unroll
        for (int j = 0; j < 4; ++j)
            part[wv * 16 + lk * 4 + j][n * 16 + lrow] = acc[n][j];
    }
    __syncthreads();

    // Epilogue: wave 0, lane = row. Add noise, top-2, gates.
    if (wv == 0) {
        const int r   = l;
        const int row = brow + r;
        float m1 = -1e30f, m2 = -1e30f;
        int i1 = 0, i2 = 0;
        #pragma unroll
        for (int j = 0; j < NEXP; j += 4) {
            float4 s4       = *reinterpret_cast<const float4*>(&part[r][j]);
            const float4 nv = *reinterpret_cast<const float4*>(&nsh[r][j]);
            s4.x += nv.x; s4.y += nv.y; s4.z += nv.z; s4.w += nv.w;
            if (s4.x > m1) { m2 = m1; i2 = i1; m1 = s4.x; i1 = j + 0; } else if (s4.x > m2) { m2 = s4.x; i2 = j + 0; }
            if (s4.y > m1) { m2 = m1; i2 = i1; m1 = s4.y; i1 = j + 1; } else if (s4.y > m2) { m2 = s4.y; i2 = j + 1; }
            if (s4.z > m1) { m2 = m1; i2 = i1; m1 = s4.z; i1 = j + 2; } else if (s4.z > m2) { m2 = s4.z; i2 = j + 2; }
            if (s4.w > m1) { m2 = m1; i2 = i1; m1 = s4.w; i1 = j + 3; } else if (s4.w > m2) { m2 = s4.w; i2 = j + 3; }
        }

        // Softmax Z cancels under top-2 renorm: g1 = 1/(1+exp(l2-l1)).
        const float t  = expf(m2 - m1);
        const float g1 = 1.0f / (1.0f + t);
        const float g2 = 1.0f - g1;

        out[OFF_IDX + row * 2 + 0]   = (float)i1;
        out[OFF_IDX + row * 2 + 1]   = (float)i2;
        out[OFF_GATES + row * 2 + 0] = g1;
        out[OFF_GATES + row * 2 + 1] = g2;

        g1s[r] = g1; g2s[r] = g2; i1s[r] = i1; i2s[r] = i2;
        atomicAdd(&bins[i1], 1.0f);
        atomicAdd(&bins[i2], 1.0f);
    }
    __syncthreads();

    // Combine tile write: 256 threads x 4 rounds, fully coalesced 16 KB.
    #pragma unroll
    for (int i = 0; i < 4; ++i) {
        const int idx = tid + i * 256;
        const int r = idx >> 4, c = (idx & 15) * 4;
        const int   a  = i1s[r], b = i2s[r];
        const float ga = g1s[r], gb = g2s[r];
        float4 v;
        v.x = (c + 0 == a) ? ga : (c + 0 == b) ? gb : 0.0f;
        v.y = (c + 1 == a) ? ga : (c + 1 == b) ? gb : 0.0f;
        v.z = (c + 2 == a) ? ga : (c + 2 == b) ? gb : 0.0f;
        v.w = (c + 3 == a) ? ga : (c + 3 == b) ? gb : 0.0f;
        *reinterpret_cast<float4*>(
            out + OFF_COMBINE + (size_t)(brow + r) * NEXP + c) = v;
    }

    if (tid < NEXP) {
        const float v = bins[tid];
        if (v != 0.0f) atomicAdd(out + OFF_ACT + tid, v);
    }
}

extern "C" void kernel_launch(void* const* d_in, const int* in_sizes, int n_in,
                              void* d_out, int out_size, void* d_ws, size_t ws_size,
                              hipStream_t stream) {
    const float* x     = (const float*)d_in[0];
    const float* wg    = (const float*)d_in[1];
    const float* noise = (const float*)d_in[2];
    float* out = (float*)d_out;

    wsplit_kernel<<<DIM / 16, 256, 0, stream>>>(wg, out);
    router_kernel<<<T_TOKENS / 64, 256, 0, stream>>>(x, noise, out);
}

// Round 3
// 251.536 us; speedup vs baseline: 1.2266x; 1.2266x over previous
//
#include <hip/hip_runtime.h>
#include <math.h>

// Problem constants (from reference setup_inputs)
#define T_TOKENS 16384
#define DIM      2048
#define NEXP     64
#define TOPK     2

// Flat fp32 output layout: combine | topk_idx | gates | expert_activation
#define OFF_COMBINE 0
#define OFF_IDX     (T_TOKENS * NEXP)
#define OFF_GATES   (OFF_IDX + T_TOKENS * TOPK)
#define OFF_ACT     (OFF_GATES + T_TOKENS * TOPK)

#define PSTR 68                 // padded LDS row stride (floats); 272B = 17*16B
#define WT_PLANE (NEXP * DIM)   // one bf16 plane of transposed w, in elements

#define NKC   4                 // K-split chunks
#define KC    (DIM / NKC)       // 512 k's per wave
#define NSTEP (KC / 32)         // 16 K-steps of 32

typedef __attribute__((ext_vector_type(8))) short  short8;   // 8 bf16 in 4 VGPRs
typedef __attribute__((ext_vector_type(4))) float  f32x4;

#define MFMA16(a, b, c) __builtin_amdgcn_mfma_f32_16x16x32_bf16((a), (b), (c), 0, 0, 0)

// Static device storage: 3 bf16 planes (h,m,l) of wt[e][k] = 768 KB.
__device__ __align__(16) unsigned short g_wt[3 * WT_PLANE];

// ---------------------------------------------------------------------------
// Setup: transpose w [DIM][NEXP] -> wt[e][k], 3-way bf16 TRUNCATION split.
// h = top16(v); r1 = v-h exact; m = top16(r1); r2 = r1-m exact; l = top16(r2).
// Coalesced writes: one block per expert, thread t owns k = 8t..8t+7 (16B
// contiguous per plane). v2's wsplit wrote 2B at stride 4KB -> ~140us; this
// version is ~5us.
// ---------------------------------------------------------------------------
__global__ void wsplit_kernel(const float* __restrict__ w,
                              float* __restrict__ out) {
    const int tid = threadIdx.x;           // 0..255
    const int e   = blockIdx.x;            // 0..63
    if (e == 0 && tid < NEXP) out[OFF_ACT + tid] = 0.0f;

    const int k0 = tid * 8;
    short8 hs, ms, ls;
    #pragma unroll
    for (int i = 0; i < 8; ++i) {
        const float v = w[(size_t)(k0 + i) * NEXP + e];
        const unsigned int bv = __builtin_bit_cast(unsigned int, v);
        const unsigned int hb = bv & 0xFFFF0000u;
        const float r1 = v - __builtin_bit_cast(float, hb);
        const unsigned int r1b = __builtin_bit_cast(unsigned int, r1);
        const unsigned int mb = r1b & 0xFFFF0000u;
        const float r2 = r1 - __builtin_bit_cast(float, mb);
        const unsigned int lb = __builtin_bit_cast(unsigned int, r2);
        hs[i] = (short)(hb >> 16);
        ms[i] = (short)(mb >> 16);
        ls[i] = (short)(lb >> 16);
    }
    *reinterpret_cast<short8*>(&g_wt[(size_t)e * DIM + k0])                = hs;
    *reinterpret_cast<short8*>(&g_wt[(size_t)e * DIM + k0 + WT_PLANE])     = ms;
    *reinterpret_cast<short8*>(&g_wt[(size_t)e * DIM + k0 + 2 * WT_PLANE]) = ls;
}

__device__ __forceinline__ void gload_lds16(const float* g, float* s) {
    __builtin_amdgcn_global_load_lds(
        (const __attribute__((address_space(1))) void*)g,
        (__attribute__((address_space(3))) void*)s, 16, 0, 0);
}

// fp32x8 -> truncation split (ah, am, al)
__device__ __forceinline__ void split8(const float4 a, const float4 b,
                                       short8& ah, short8& am, short8& al) {
    float v[8] = {a.x, a.y, a.z, a.w, b.x, b.y, b.z, b.w};
    #pragma unroll
    for (int i = 0; i < 8; ++i) {
        const unsigned int bv = __builtin_bit_cast(unsigned int, v[i]);
        const unsigned int hb = bv & 0xFFFF0000u;
        const float r1 = v[i] - __builtin_bit_cast(float, hb);
        const unsigned int r1b = __builtin_bit_cast(unsigned int, r1);
        const unsigned int mb = r1b & 0xFFFF0000u;
        const float r2 = r1 - __builtin_bit_cast(float, mb);
        const unsigned int lb = __builtin_bit_cast(unsigned int, r2);
        ah[i] = (short)(hb >> 16);
        am[i] = (short)(mb >> 16);
        al[i] = (short)(lb >> 16);
    }
}

// ---------------------------------------------------------------------------
// Router: block = 64 tokens, 512 threads = 8 waves = 2 token-halves (M=32
// per wave) x 4 K-chunks (512 k each). Grid 256 = 1 block/CU, 8 waves/CU =
// 2/SIMD (TLP doubled vs v2). Per wave: 2 A-frags x 4 e-frags x 6
// split-products = 48 MFMA per 32-k step, 16 steps.
//   A path: global_load_lds -> LDS (per-wave private, depth-2 double buffer,
//   explicit vmcnt(0) fence at step top; prefetch for s+1 rides over all of
//   step s's compute). W path: short8 register loads from L2-resident g_wt.
//   K-partials reduced via LDS `part`, aliased onto the x-stage pool behind
//   a barrier.
// ---------------------------------------------------------------------------
__global__ __launch_bounds__(512, 2)
void router_kernel(const float* __restrict__ x,
                   const float* __restrict__ noise,
                   float* __restrict__ out) {
    // pool: x-stage during K-loop (8 waves x 2 buf x 4KB = 64KB),
    // then part[NKC][64][PSTR] fp32 (69.6KB) after a barrier.
    __shared__ __align__(16) float pool[NKC * 64 * PSTR];
    __shared__ __align__(16) float nsh[64][PSTR];
    __shared__ float g1s[64], g2s[64];
    __shared__ int   i1s[64], i2s[64];
    __shared__ float bins[NEXP];

    const int tid  = threadIdx.x;
    const int l    = tid & 63;
    const int wv   = __builtin_amdgcn_readfirstlane(tid >> 6);  // 0..7
    const int lrow = l & 15;          // MFMA fragment row/col
    const int lk   = l >> 4;          // k-subgroup (0..3)
    const int mt   = wv & 1;          // token half (32 tokens)
    const int kc   = wv >> 1;         // K chunk
    const int brow = blockIdx.x * 64;

    if (tid < NEXP) bins[tid] = 0.0f;

    // Stage noise rows, coalesced (1024 float4s over 512 threads).
    #pragma unroll
    for (int i = 0; i < 2; ++i) {
        const int idx = tid + i * 512;
        const int r = idx >> 4, c = (idx & 15) * 4;
        *reinterpret_cast<float4*>(&nsh[r][c]) =
            *reinterpret_cast<const float4*>(noise + (size_t)(brow + r) * NEXP + c);
    }

    // Per-wave x-stage region: 2048 floats (2 bufs x 1024).
    float* xs = pool + wv * 2048;
    // Global x row pointers for the two A-frags of this wave.
    const float* xg0 = x + (size_t)(brow + mt * 32 + lrow) * DIM + kc * KC + lk * 8;
    const float* xg1 = x + (size_t)(brow + mt * 32 + 16 + lrow) * DIM + kc * KC + lk * 8;

    // W fragment pointers (per e-frag), bf16 planes at +0/+WT_PLANE/+2*WT_PLANE.
    const unsigned short* wb[4];
    #pragma unroll
    for (int n = 0; n < 4; ++n)
        wb[n] = g_wt + (size_t)(n * 16 + lrow) * DIM + kc * KC + lk * 8;

    f32x4 acc[2][4];
    #pragma unroll
    for (int f = 0; f < 2; ++f)
        #pragma unroll
        for (int n = 0; n < 4; ++n) acc[f][n] = (f32x4){0.f, 0.f, 0.f, 0.f};

    // Stage step t into buf b: 4 x 1KB ops (frag0 h0/h1, frag1 h0/h1).
    // LDS dest is wave-uniform base; HW writes base + lane*16.
#define STAGE(b, t) do {                                              \
        const int _ko = (t) * 32;                                     \
        gload_lds16(xg0 + _ko,     xs + (b) * 1024 + 0 * 256);        \
        gload_lds16(xg0 + _ko + 4, xs + (b) * 1024 + 1 * 256);        \
        gload_lds16(xg1 + _ko,     xs + (b) * 1024 + 2 * 256);        \
        gload_lds16(xg1 + _ko + 4, xs + (b) * 1024 + 3 * 256);        \
    } while (0)

    STAGE(0, 0);

    #pragma unroll 2
    for (int s = 0; s < NSTEP; ++s) {
        const int b = s & 1;

        // Fence: stage for this buf (issued last step) must have landed.
        asm volatile("s_waitcnt vmcnt(0)" ::: "memory");

        // Read back this step's A data (lane's own 16B slots).
        const float4 xa0 = *reinterpret_cast<const float4*>(xs + b * 1024 +       l * 4);
        const float4 xa1 = *reinterpret_cast<const float4*>(xs + b * 1024 + 256 + l * 4);
        const float4 xa2 = *reinterpret_cast<const float4*>(xs + b * 1024 + 512 + l * 4);
        const float4 xa3 = *reinterpret_cast<const float4*>(xs + b * 1024 + 768 + l * 4);

        // Prefetch next step (stays in flight across all compute below).
        const int tn = (s + 1 < NSTEP) ? (s + 1) : s;   // tail: harmless restage
        STAGE(b ^ 1, tn);

        // W fragments for this step (L2-resident).
        short8 Wh[4], Wm[4], Wl[4];
        #pragma unroll
        for (int n = 0; n < 4; ++n) {
            const unsigned short* p = wb[n] + s * 32;
            Wh[n] = *reinterpret_cast<const short8*>(p);
            Wm[n] = *reinterpret_cast<const short8*>(p + WT_PLANE);
            Wl[n] = *reinterpret_cast<const short8*>(p + 2 * WT_PLANE);
        }

        // fp32 -> bf16 truncation splits.
        short8 a0h, a0m, a0l, a1h, a1m, a1l;
        split8(xa0, xa1, a0h, a0m, a0l);
        split8(xa2, xa3, a1h, a1m, a1l);

        // 6 split-products per (frag, e-frag): h*h + h*m + m*h + h*l + m*m + l*h
        #pragma unroll
        for (int n = 0; n < 4; ++n) {
            acc[0][n] = MFMA16(a0h, Wh[n], acc[0][n]);
            acc[0][n] = MFMA16(a0h, Wm[n], acc[0][n]);
            acc[0][n] = MFMA16(a0m, Wh[n], acc[0][n]);
            acc[0][n] = MFMA16(a0h, Wl[n], acc[0][n]);
            acc[0][n] = MFMA16(a0m, Wm[n], acc[0][n]);
            acc[0][n] = MFMA16(a0l, Wh[n], acc[0][n]);
            acc[1][n] = MFMA16(a1h, Wh[n], acc[1][n]);
            acc[1][n] = MFMA16(a1h, Wm[n], acc[1][n]);
            acc[1][n] = MFMA16(a1m, Wh[n], acc[1][n]);
            acc[1][n] = MFMA16(a1h, Wl[n], acc[1][n]);
            acc[1][n] = MFMA16(a1m, Wm[n], acc[1][n]);
            acc[1][n] = MFMA16(a1l, Wh[n], acc[1][n]);
        }
    }
#undef STAGE

    // All waves done with x-stage (compiler drains vmcnt before s_barrier),
    // then pool becomes part[NKC][64][PSTR].
    __syncthreads();

    // C/D layout (m89-verified): col = lane&15, row = (lane>>4)*4 + reg.
    #pragma unroll
    for (int f = 0; f < 2; ++f)
        #pragma unroll
        for (int n = 0; n < 4; ++n)
            #pragma unroll
            for (int j = 0; j < 4; ++j)
                pool[((size_t)kc * 64 + (mt * 32 + f * 16 + lk * 4 + j)) * PSTR
                     + (n * 16 + lrow)] = acc[f][n][j];
    __syncthreads();

    // Epilogue: wave 0, lane = row. Sum K-partials, add noise, top-2, gates.
    if (wv == 0) {
        const int r   = l;
        const int row = brow + r;
        float m1 = -1e30f, m2 = -1e30f;
        int i1 = 0, i2 = 0;
        #pragma unroll
        for (int j = 0; j < NEXP; j += 4) {
            float4 s4       = *reinterpret_cast<const float4*>(&pool[(0 * 64 + r) * PSTR + j]);
            const float4 p1 = *reinterpret_cast<const float4*>(&pool[(1 * 64 + r) * PSTR + j]);
            const float4 p2 = *reinterpret_cast<const float4*>(&pool[(2 * 64 + r) * PSTR + j]);
            const float4 p3 = *reinterpret_cast<const float4*>(&pool[(3 * 64 + r) * PSTR + j]);
            const float4 nv = *reinterpret_cast<const float4*>(&nsh[r][j]);
            s4.x += p1.x + p2.x + p3.x + nv.x;
            s4.y += p1.y + p2.y + p3.y + nv.y;
            s4.z += p1.z + p2.z + p3.z + nv.z;
            s4.w += p1.w + p2.w + p3.w + nv.w;
            if (s4.x > m1) { m2 = m1; i2 = i1; m1 = s4.x; i1 = j + 0; } else if (s4.x > m2) { m2 = s4.x; i2 = j + 0; }
            if (s4.y > m1) { m2 = m1; i2 = i1; m1 = s4.y; i1 = j + 1; } else if (s4.y > m2) { m2 = s4.y; i2 = j + 1; }
            if (s4.z > m1) { m2 = m1; i2 = i1; m1 = s4.z; i1 = j + 2; } else if (s4.z > m2) { m2 = s4.z; i2 = j + 2; }
            if (s4.w > m1) { m2 = m1; i2 = i1; m1 = s4.w; i1 = j + 3; } else if (s4.w > m2) { m2 = s4.w; i2 = j + 3; }
        }

        // Softmax Z cancels under top-2 renorm: g1 = 1/(1+exp(l2-l1)).
        const float t  = expf(m2 - m1);
        const float g1 = 1.0f / (1.0f + t);
        const float g2 = 1.0f - g1;

        out[OFF_IDX + row * 2 + 0]   = (float)i1;
        out[OFF_IDX + row * 2 + 1]   = (float)i2;
        out[OFF_GATES + row * 2 + 0] = g1;
        out[OFF_GATES + row * 2 + 1] = g2;

        g1s[r] = g1; g2s[r] = g2; i1s[r] = i1; i2s[r] = i2;
        atomicAdd(&bins[i1], 1.0f);
        atomicAdd(&bins[i2], 1.0f);
    }
    __syncthreads();

    // Combine tile write: 512 threads x 2 rounds, fully coalesced 16 KB.
    #pragma unroll
    for (int i = 0; i < 2; ++i) {
        const int idx = tid + i * 512;
        const int r = idx >> 4, c = (idx & 15) * 4;
        const int   a  = i1s[r], b = i2s[r];
        const float ga = g1s[r], gb = g2s[r];
        float4 v;
        v.x = (c + 0 == a) ? ga : (c + 0 == b) ? gb : 0.0f;
        v.y = (c + 1 == a) ? ga : (c + 1 == b) ? gb : 0.0f;
        v.z = (c + 2 == a) ? ga : (c + 2 == b) ? gb : 0.0f;
        v.w = (c + 3 == a) ? ga : (c + 3 == b) ? gb : 0.0f;
        *reinterpret_cast<float4*>(
            out + OFF_COMBINE + (size_t)(brow + r) * NEXP + c) = v;
    }

    if (tid < NEXP) {
        const float v = bins[tid];
        if (v != 0.0f) atomicAdd(out + OFF_ACT + tid, v);
    }
}

extern "C" void kernel_launch(void* const* d_in, const int* in_sizes, int n_in,
                              void* d_out, int out_size, void* d_ws, size_t ws_size,
                              hipStream_t stream) {
    const float* x     = (const float*)d_in[0];
    const float* wg    = (const float*)d_in[1];
    const float* noise = (const float*)d_in[2];
    float* out = (float*)d_out;

    wsplit_kernel<<<NEXP, 256, 0, stream>>>(wg, out);
    router_kernel<<<T_TOKENS / 64, 512, 0, stream>>>(x, noise, out);
}